// Round 2
// baseline (1821.501 us; speedup 1.0000x reference)
//
#include <hip/hip_runtime.h>

// ---------------------------------------------------------------------------
// Swin window-attention block, MI355X.  B=8 H=W=112 C=384 NH=12 hd=32 WS=7
// SS=3 -> N=49, nW=256, Bw=2048, rows=100352.
//
// Round-4: k1/k3 were occupancy-capped by LDS (48 KB B-tile -> 3 blocks/CU,
// 31% occupancy; MfmaUtil 16%).  Fix: stage B in two K-halves (24 KB buffer)
// -> 6 blocks/CU (~75% occupancy target), A-prefetch ring carries across the
// mid-loop barriers.  Epilogue transpose runs in two 128-row passes to fit
// 24 KB.  k3 gets the same split + an explicit A ring.  k0/k0x/k2 unchanged.
// ---------------------------------------------------------------------------

typedef __bf16 bf16;
typedef __bf16 bf16x8 __attribute__((ext_vector_type(8)));
typedef float  f32x4  __attribute__((ext_vector_type(4)));

#define MFMA16(a, b, c) __builtin_amdgcn_mfma_f32_16x16x32_bf16((a), (b), (c), 0, 0, 0)

static __device__ __forceinline__ bf16x8 cvt8(const float4 lo, const float4 hi) {
    bf16x8 r;
    r[0] = (bf16)lo.x; r[1] = (bf16)lo.y; r[2] = (bf16)lo.z; r[3] = (bf16)lo.w;
    r[4] = (bf16)hi.x; r[5] = (bf16)hi.y; r[6] = (bf16)hi.z; r[7] = (bf16)hi.w;
    return r;
}

// ---------------------------------------------------------------------------
// k0: prep weights + bias table (unchanged, proven correct).
// ---------------------------------------------------------------------------
__global__ __launch_bounds__(256) void k0_prep(
    const float* __restrict__ qkv_w, const float* __restrict__ proj_w,
    const float* __restrict__ rpt,
    bf16* __restrict__ w1t, bf16* __restrict__ w2t, float* __restrict__ BT)
{
    unsigned tid = blockIdx.x * 256u + threadIdx.x;
    if (tid < 442368u) {                       // w1t[n][k] = qkv_w[k][n] (*scale for Q)
        unsigned n = tid / 384u, k = tid - n * 384u;
        float v = qkv_w[k * 1152u + n];
        if (n < 384u) v *= 0.17677669529663687f;
        w1t[tid] = (bf16)v;
    } else if (tid < 589824u) {                // w2t[n][k] = proj_w[k][n]
        unsigned i = tid - 442368u;
        unsigned n = i / 384u, k = i - n * 384u;
        w2t[i] = (bf16)proj_w[k * 384u + n];
    } else if (tid < 638976u) {                // BT[h][b][a]
        unsigned i = tid - 589824u;
        unsigned h = i >> 12, r = i & 4095u, b = r >> 6, a = r & 63u;
        float v;
        if (b >= 49u) v = -1e9f;
        else if (a >= 49u) v = 0.0f;
        else {
            int ia = (int)(a / 7u), ja = (int)(a - 7u * (a / 7u));
            int ib = (int)(b / 7u), jb = (int)(b - 7u * (b / 7u));
            int ridx = 84 + 13 * (ia - ib) + (ja - jb);
            v = rpt[ridx * 12 + (int)h];
        }
        BT[i] = v;
    }
}

// ---------------------------------------------------------------------------
// k0x: X f32 -> bf16, 38,535,168 elems; grid 18816*256 threads * 8 elems.
// ---------------------------------------------------------------------------
__global__ __launch_bounds__(256) void k0x_cvt(
    const float* __restrict__ X, bf16* __restrict__ Xb)
{
    size_t base = ((size_t)blockIdx.x * 256u + threadIdx.x) * 8u;
    float4 lo = *(const float4*)(X + base);
    float4 hi = *(const float4*)(X + base + 4);
    *(bf16x8*)(Xb + base) = cvt8(lo, hi);
}

// ---------------------------------------------------------------------------
// k1: Y[100352][1152](bf16) = Xb(bf16) @ W1t^T + b.  BM=256 (4 waves),
// BN=64.  B staged in two 24 KB K-halves -> 6 blocks/CU; barrier-free
// compute within each half; 3-slot A register ring spans the restage.
// grid = 392*18 = 7056, XCD-swizzled.
// ---------------------------------------------------------------------------
__global__ __launch_bounds__(256, 6) void k1_qkv_b(
    const bf16* __restrict__ X, const bf16* __restrict__ W,
    const float* __restrict__ bias, bf16* __restrict__ Y)
{
    __shared__ __align__(16) bf16 Bs[12288];   // 24 KB: half B tile / epi buf
    unsigned id = blockIdx.x;                  // 7056 = 8 xcd * 49 mi * 18 n
    unsigned xcd = id & 7u, seq = id >> 3;
    unsigned mi = seq / 18u, nb = seq - mi * 18u;
    unsigned mblk = xcd + (mi << 3);
    unsigned tid = threadIdx.x;
    unsigned lane = tid & 63u, wv = tid >> 6;
    unsigned ln = lane & 15u, lq = lane >> 4;
    unsigned m0 = mblk * 256u, n0 = nb * 64u;

    // ---- stage B K-half 0: rows(n) 0..63 x lk 0..191, fragment layout ----
    for (unsigned c = tid; c < 1536u; c += 256u) {
        unsigned row = c / 24u, kc = c - row * 24u, lk = kc * 8u;
        unsigned blk = (lk >> 5) * 4u + (row >> 4);          // 0..23
        unsigned l = (row & 15u) | ((kc & 3u) << 4);
        *(int4*)&Bs[(blk * 64u + l) * 8u] =
            *(const int4*)(W + (size_t)(n0 + row) * 384u + lk);
    }

    f32x4 acc[4][4] = {};
    unsigned rbase = m0 + wv * 64u;
    const bf16* Ab = X + (size_t)(rbase + ln) * 384u + lq * 8u;

    // 3-slot prefetch ring (indices compile-time under full unroll)
    bf16x8 af[3][4];
#pragma unroll
    for (unsigned i = 0; i < 4; ++i) af[0][i] = *(const bf16x8*)(Ab + i * 6144u);
#pragma unroll
    for (unsigned i = 0; i < 4; ++i) af[1][i] = *(const bf16x8*)(Ab + 32u + i * 6144u);

    __syncthreads();

    // ---- compute half 0: kt = 0..5 ----
#pragma unroll
    for (unsigned kt = 0; kt < 6; ++kt) {
#pragma unroll
        for (unsigned i = 0; i < 4; ++i)
            af[(kt + 2u) % 3u][i] = *(const bf16x8*)(Ab + (kt + 2u) * 32u + i * 6144u);
        bf16x8 bfr[4];
#pragma unroll
        for (unsigned j = 0; j < 4; ++j)
            bfr[j] = *(const bf16x8*)&Bs[((kt * 4u + j) * 64u + lane) * 8u];
#pragma unroll
        for (unsigned i = 0; i < 4; ++i)
#pragma unroll
            for (unsigned j = 0; j < 4; ++j)
                acc[i][j] = MFMA16(af[kt % 3u][i], bfr[j], acc[i][j]);
    }

    __syncthreads();                            // all waves done reading half 0

    // ---- stage B K-half 1: lk 192..383 ----
    for (unsigned c = tid; c < 1536u; c += 256u) {
        unsigned row = c / 24u, kc = c - row * 24u, lk = kc * 8u;
        unsigned blk = (lk >> 5) * 4u + (row >> 4);
        unsigned l = (row & 15u) | ((kc & 3u) << 4);
        *(int4*)&Bs[(blk * 64u + l) * 8u] =
            *(const int4*)(W + (size_t)(n0 + row) * 384u + 192u + lk);
    }
    __syncthreads();

    // ---- compute half 1: kt = 6..11 (ring already holds kt=6,7) ----
#pragma unroll
    for (unsigned kt = 6; kt < 12; ++kt) {
        if (kt < 10u) {
#pragma unroll
            for (unsigned i = 0; i < 4; ++i)
                af[(kt + 2u) % 3u][i] = *(const bf16x8*)(Ab + (kt + 2u) * 32u + i * 6144u);
        }
        bf16x8 bfr[4];
#pragma unroll
        for (unsigned j = 0; j < 4; ++j)
            bfr[j] = *(const bf16x8*)&Bs[(((kt - 6u) * 4u + j) * 64u + lane) * 8u];
#pragma unroll
        for (unsigned i = 0; i < 4; ++i)
#pragma unroll
            for (unsigned j = 0; j < 4; ++j)
                acc[i][j] = MFMA16(af[kt % 3u][i], bfr[j], acc[i][j]);
    }

    // bias (Q cols pre-scaled)
    float bv[4];
#pragma unroll
    for (unsigned j = 0; j < 4; ++j) {
        unsigned col = n0 + j * 16u + ln;
        bv[j] = bias[col];
        if (col < 384u) bv[j] *= 0.17677669529663687f;
    }

    // ---- epilogue: transpose through LDS in two 128-row passes ----
    __syncthreads();
#pragma unroll
    for (unsigned p = 0; p < 2; ++p) {
        if ((wv >> 1) == p) {
            unsigned rloc = (wv & 1u) * 64u;
#pragma unroll
            for (unsigned i = 0; i < 4; ++i)
#pragma unroll
                for (unsigned j = 0; j < 4; ++j)
#pragma unroll
                    for (unsigned rg = 0; rg < 4; ++rg) {
                        unsigned r = rloc + i * 16u + lq * 4u + rg;
                        Bs[r * 72u + j * 16u + ln] = (bf16)(acc[i][j][rg] + bv[j]);
                    }
        }
        __syncthreads();
#pragma unroll
        for (unsigned it = 0; it < 4; ++it) {
            unsigned idx = it * 256u + tid;
            unsigned row = idx >> 3, c8 = (idx & 7u) * 8u;
            *(bf16x8*)(Y + (size_t)(m0 + p * 128u + row) * 1152u + n0 + c8) =
                *(const bf16x8*)&Bs[row * 72u + c8];
        }
        __syncthreads();
    }
}

// ---------------------------------------------------------------------------
// k2: one wave per (window, head).  grid = (12, 2048), block = 64.
// Writes attn-out bf16 into Y's Q-slot (cols [0,384)).  (unchanged)
// ---------------------------------------------------------------------------
__global__ __launch_bounds__(64) void k2_attn(
    bf16* __restrict__ Y, const float* __restrict__ BT)
{
    __shared__ __align__(16) bf16 Pl[64 * 72];
    __shared__ __align__(16) bf16 Vt[32 * 72];
    unsigned h = blockIdx.x, bwin = blockIdx.y;
    unsigned bb = bwin >> 8, wi = bwin & 255u, wh = wi >> 4, ww = wi & 15u;
    unsigned lane = threadIdx.x, ln = lane & 15u, lq = lane >> 4;
    unsigned hw32 = h * 32u;

    auto pixrow = [&](unsigned t) -> unsigned {
        unsigned ti = t / 7u, tj = t - ti * 7u;
        unsigned gh = wh * 7u + ti + 3u; if (gh >= 112u) gh -= 112u;
        unsigned gw = ww * 7u + tj + 3u; if (gw >= 112u) gw -= 112u;
        return bb * 12544u + gh * 112u + gw;
    };

    // V -> LDS transposed
    {
        unsigned t = lane < 49u ? lane : 0u;
        const bf16* vs = Y + (size_t)pixrow(t) * 1152u + 768u + hw32;
        bf16x8 v0 = *(const bf16x8*)(vs);
        bf16x8 v1 = *(const bf16x8*)(vs + 8);
        bf16x8 v2 = *(const bf16x8*)(vs + 16);
        bf16x8 v3 = *(const bf16x8*)(vs + 24);
#pragma unroll
        for (int d = 0; d < 8; ++d) {
            Vt[(unsigned)(d     ) * 72u + lane] = v0[d];
            Vt[(unsigned)(d + 8 ) * 72u + lane] = v1[d];
            Vt[(unsigned)(d + 16) * 72u + lane] = v2[d];
            Vt[(unsigned)(d + 24) * 72u + lane] = v3[d];
        }
    }

    bf16x8 qf[4], kf[4];
#pragma unroll
    for (int i = 0; i < 4; ++i) {
        unsigned t = (unsigned)i * 16u + ln; t = t < 49u ? t : 0u;
        qf[i] = *(const bf16x8*)(Y + (size_t)pixrow(t) * 1152u + hw32 + lq * 8u);
    }
#pragma unroll
    for (int i = 0; i < 4; ++i) {
        unsigned t = (unsigned)i * 16u + ln; t = t < 49u ? t : 0u;
        kf[i] = *(const bf16x8*)(Y + (size_t)pixrow(t) * 1152u + 384u + hw32 + lq * 8u);
    }

    f32x4 s[4][4] = {};
#pragma unroll
    for (int i = 0; i < 4; ++i)
#pragma unroll
        for (int j = 0; j < 4; ++j)
            s[i][j] = MFMA16(qf[i], kf[j], s[i][j]);

    const float* bth = BT + h * 4096u;
#pragma unroll
    for (int i = 0; i < 4; ++i)
#pragma unroll
        for (int j = 0; j < 4; ++j) {
            f32x4 b = *(const f32x4*)(bth + ((unsigned)j * 16u + ln) * 64u +
                                      (unsigned)i * 16u + lq * 4u);
            s[i][j] += b;
        }

    if (wh == 15u || ww == 15u) {
        int ra[4][4], rb[4];
#pragma unroll
        for (int i = 0; i < 4; ++i)
#pragma unroll
            for (int rg = 0; rg < 4; ++rg) {
                unsigned a = (unsigned)i * 16u + lq * 4u + (unsigned)rg;
                unsigned ti = a / 7u, tj = a - ti * 7u;
                unsigned gh = wh * 7u + ti, gw = ww * 7u + tj;
                int rh = gh < 105u ? 0 : (gh < 109u ? 1 : 2);
                int rw = gw < 105u ? 0 : (gw < 109u ? 1 : 2);
                ra[i][rg] = rh * 3 + rw;
            }
#pragma unroll
        for (int j = 0; j < 4; ++j) {
            unsigned bc = (unsigned)j * 16u + ln;
            unsigned ti = bc / 7u, tj = bc - ti * 7u;
            unsigned gh = wh * 7u + ti, gw = ww * 7u + tj;
            int rh = gh < 105u ? 0 : (gh < 109u ? 1 : 2);
            int rw = gw < 105u ? 0 : (gw < 109u ? 1 : 2);
            rb[j] = rh * 3 + rw;
        }
#pragma unroll
        for (int i = 0; i < 4; ++i)
#pragma unroll
            for (int j = 0; j < 4; ++j)
#pragma unroll
                for (int rg = 0; rg < 4; ++rg)
                    if (ra[i][rg] != rb[j]) s[i][j][rg] -= 100.0f;
    }

    float rinv[4][4];
#pragma unroll
    for (int i = 0; i < 4; ++i)
#pragma unroll
        for (int rg = 0; rg < 4; ++rg) {
            float m = fmaxf(fmaxf(s[i][0][rg], s[i][1][rg]),
                            fmaxf(s[i][2][rg], s[i][3][rg]));
#pragma unroll
            for (int d = 8; d >= 1; d >>= 1) m = fmaxf(m, __shfl_xor(m, d, 64));
            float sum = 0.0f;
#pragma unroll
            for (int j = 0; j < 4; ++j) {
                float e = __expf(s[i][j][rg] - m);
                s[i][j][rg] = e;
                sum += e;
            }
#pragma unroll
            for (int d = 8; d >= 1; d >>= 1) sum += __shfl_xor(sum, d, 64);
            rinv[i][rg] = 1.0f / sum;
        }

#pragma unroll
    for (int i = 0; i < 4; ++i)
#pragma unroll
        for (int rg = 0; rg < 4; ++rg) {
            unsigned a = (unsigned)i * 16u + lq * 4u + (unsigned)rg;
#pragma unroll
            for (int j = 0; j < 4; ++j)
                Pl[a * 72u + (unsigned)j * 16u + ln] = (bf16)s[i][j][rg];
        }

    __syncthreads();

    f32x4 o[4][2] = {};
#pragma unroll
    for (int ks = 0; ks < 2; ++ks) {
        bf16x8 pf[4], vf[2];
#pragma unroll
        for (int i = 0; i < 4; ++i)
            pf[i] = *(const bf16x8*)&Pl[((unsigned)i * 16u + ln) * 72u +
                                        (unsigned)ks * 32u + lq * 8u];
#pragma unroll
        for (int c = 0; c < 2; ++c)
            vf[c] = *(const bf16x8*)&Vt[((unsigned)c * 16u + ln) * 72u +
                                        (unsigned)ks * 32u + lq * 8u];
#pragma unroll
        for (int i = 0; i < 4; ++i)
#pragma unroll
            for (int c = 0; c < 2; ++c)
                o[i][c] = MFMA16(pf[i], vf[c], o[i][c]);
    }

#pragma unroll
    for (int i = 0; i < 4; ++i)
#pragma unroll
        for (int rg = 0; rg < 4; ++rg) {
            unsigned a = (unsigned)i * 16u + lq * 4u + (unsigned)rg;
            if (a < 49u) {
                float ri = rinv[i][rg];
                size_t base = (size_t)pixrow(a) * 1152u + hw32;
                Y[base + ln]       = (bf16)(o[i][0][rg] * ri);
                Y[base + 16u + ln] = (bf16)(o[i][1][rg] * ri);
            }
        }
}

// ---------------------------------------------------------------------------
// k3: Out[100352][384](f32) = Ab(bf16, Y's Q-slot) @ W2t^T + b.
// Same split-K staging (24 KB, 6 blocks/CU) + 3-slot A ring.
// grid = 392*6 = 2352.
// ---------------------------------------------------------------------------
__global__ __launch_bounds__(256, 6) void k3_proj(
    const bf16* __restrict__ A, const bf16* __restrict__ W,
    const float* __restrict__ bias, float* __restrict__ Out)
{
    __shared__ __align__(16) bf16 Bs[12288];
    unsigned id = blockIdx.x;                  // 2352 = 8 xcd * 49 mi * 6 n
    unsigned xcd = id & 7u, seq = id >> 3;
    unsigned mi = seq / 6u, nb = seq - mi * 6u;
    unsigned mblk = xcd + (mi << 3);
    unsigned tid = threadIdx.x;
    unsigned lane = tid & 63u, wv = tid >> 6;
    unsigned ln = lane & 15u, lq = lane >> 4;
    unsigned m0 = mblk * 256u, n0 = nb * 64u;

    for (unsigned c = tid; c < 1536u; c += 256u) {
        unsigned row = c / 24u, kc = c - row * 24u, lk = kc * 8u;
        unsigned blk = (lk >> 5) * 4u + (row >> 4);
        unsigned l = (row & 15u) | ((kc & 3u) << 4);
        *(int4*)&Bs[(blk * 64u + l) * 8u] =
            *(const int4*)(W + (size_t)(n0 + row) * 384u + lk);
    }

    f32x4 acc[4][4] = {};
    unsigned rbase = m0 + wv * 64u;
    const bf16* Ab = A + (size_t)(rbase + ln) * 1152u + lq * 8u;

    bf16x8 af[3][4];
#pragma unroll
    for (unsigned i = 0; i < 4; ++i) af[0][i] = *(const bf16x8*)(Ab + i * 18432u);
#pragma unroll
    for (unsigned i = 0; i < 4; ++i) af[1][i] = *(const bf16x8*)(Ab + 32u + i * 18432u);

    __syncthreads();

#pragma unroll
    for (unsigned kt = 0; kt < 6; ++kt) {
#pragma unroll
        for (unsigned i = 0; i < 4; ++i)
            af[(kt + 2u) % 3u][i] = *(const bf16x8*)(Ab + (kt + 2u) * 32u + i * 18432u);
        bf16x8 bfr[4];
#pragma unroll
        for (unsigned j = 0; j < 4; ++j)
            bfr[j] = *(const bf16x8*)&Bs[((kt * 4u + j) * 64u + lane) * 8u];
#pragma unroll
        for (unsigned i = 0; i < 4; ++i)
#pragma unroll
            for (unsigned j = 0; j < 4; ++j)
                acc[i][j] = MFMA16(af[kt % 3u][i], bfr[j], acc[i][j]);
    }

    __syncthreads();

    for (unsigned c = tid; c < 1536u; c += 256u) {
        unsigned row = c / 24u, kc = c - row * 24u, lk = kc * 8u;
        unsigned blk = (lk >> 5) * 4u + (row >> 4);
        unsigned l = (row & 15u) | ((kc & 3u) << 4);
        *(int4*)&Bs[(blk * 64u + l) * 8u] =
            *(const int4*)(W + (size_t)(n0 + row) * 384u + 192u + lk);
    }
    __syncthreads();

#pragma unroll
    for (unsigned kt = 6; kt < 12; ++kt) {
        if (kt < 10u) {
#pragma unroll
            for (unsigned i = 0; i < 4; ++i)
                af[(kt + 2u) % 3u][i] = *(const bf16x8*)(Ab + (kt + 2u) * 32u + i * 18432u);
        }
        bf16x8 bfr[4];
#pragma unroll
        for (unsigned j = 0; j < 4; ++j)
            bfr[j] = *(const bf16x8*)&Bs[(((kt - 6u) * 4u + j) * 64u + lane) * 8u];
#pragma unroll
        for (unsigned i = 0; i < 4; ++i)
#pragma unroll
            for (unsigned j = 0; j < 4; ++j)
                acc[i][j] = MFMA16(af[kt % 3u][i], bfr[j], acc[i][j]);
    }

#pragma unroll
    for (unsigned j = 0; j < 4; ++j) {
        unsigned col = n0 + j * 16u + ln;
        float bv = bias[col];
#pragma unroll
        for (unsigned i = 0; i < 4; ++i) {
            unsigned row = rbase + i * 16u + lq * 4u;
#pragma unroll
            for (unsigned rg = 0; rg < 4; ++rg)
                Out[(size_t)(row + rg) * 384u + col] = acc[i][j][rg] + bv;
        }
    }
}

// ---------------------------------------------------------------------------
// launch
// ---------------------------------------------------------------------------
extern "C" void kernel_launch(void* const* d_in, const int* in_sizes, int n_in,
                              void* d_out, int out_size, void* d_ws, size_t ws_size,
                              hipStream_t stream) {
    const float* x      = (const float*)d_in[0];
    const float* qkv_w  = (const float*)d_in[1];
    const float* qkv_b  = (const float*)d_in[2];
    const float* proj_w = (const float*)d_in[3];
    const float* proj_b = (const float*)d_in[4];
    const float* rpt    = (const float*)d_in[5];
    (void)in_sizes; (void)n_in; (void)out_size; (void)ws_size;

    char* ws = (char*)d_ws;
    bf16*  Y   = (bf16*)(ws);                       // 231,211,008 B
    bf16*  w1t = (bf16*)(ws + 231211008u);          //     884,736 B
    bf16*  w2t = (bf16*)(ws + 232095744u);          //     294,912 B
    float* BT  = (float*)(ws + 232390656u);         //     196,608 B
    bf16*  Xb  = (bf16*)(ws + 232587264u);          //  77,070,336 B
    float* out = (float*)d_out;

    k0_prep<<<2496, 256, 0, stream>>>(qkv_w, proj_w, rpt, w1t, w2t, BT);
    k0x_cvt<<<18816, 256, 0, stream>>>(x, Xb);
    k1_qkv_b<<<7056, 256, 0, stream>>>(Xb, w1t, qkv_b, Y);
    k2_attn<<<dim3(12, 2048), 64, 0, stream>>>(Y, BT);
    k3_proj<<<2352, 256, 0, stream>>>(Y, w2t, proj_b, out);
}

// Round 4
// 675.610 us; speedup vs baseline: 2.6961x; 2.6961x over previous
//
#include <hip/hip_runtime.h>

// ---------------------------------------------------------------------------
// Swin window-attention block, MI355X.  B=8 H=W=112 C=384 NH=12 hd=32 WS=7
// SS=3 -> N=49, nW=256, Bw=2048, rows=100352.
//
// Round-6 = round-5 resubmit (round-5 bench died to container infra, no
// signal).  Structure: proven round-3 barrier-free GEMMs (48 KB B staged
// once, (256,3)) + two in-envelope levers:
//   - k1 A-ring depth 4 (3-kt lookahead ~234 cyc covers L2-hit latency)
//   - s_setprio(1) around MFMA clusters in k1/k3 (barrier-free waves
//     desync into load/MFMA roles -> T5's regime)
//   - k3 gets the depth-3 A ring k1 proved in round 1.
// Register arithmetic: acc 64 AGPR + ~92 VGPR < 170 cap at 3 waves/SIMD,
// no spill (round-4's spill came from __launch_bounds__(256,6), cap 85).
// ---------------------------------------------------------------------------

typedef __bf16 bf16;
typedef __bf16 bf16x8 __attribute__((ext_vector_type(8)));
typedef float  f32x4  __attribute__((ext_vector_type(4)));

#define MFMA16(a, b, c) __builtin_amdgcn_mfma_f32_16x16x32_bf16((a), (b), (c), 0, 0, 0)

static __device__ __forceinline__ bf16x8 cvt8(const float4 lo, const float4 hi) {
    bf16x8 r;
    r[0] = (bf16)lo.x; r[1] = (bf16)lo.y; r[2] = (bf16)lo.z; r[3] = (bf16)lo.w;
    r[4] = (bf16)hi.x; r[5] = (bf16)hi.y; r[6] = (bf16)hi.z; r[7] = (bf16)hi.w;
    return r;
}

// ---------------------------------------------------------------------------
// k0: prep weights + bias table (unchanged, proven correct).
// ---------------------------------------------------------------------------
__global__ __launch_bounds__(256) void k0_prep(
    const float* __restrict__ qkv_w, const float* __restrict__ proj_w,
    const float* __restrict__ rpt,
    bf16* __restrict__ w1t, bf16* __restrict__ w2t, float* __restrict__ BT)
{
    unsigned tid = blockIdx.x * 256u + threadIdx.x;
    if (tid < 442368u) {                       // w1t[n][k] = qkv_w[k][n] (*scale for Q)
        unsigned n = tid / 384u, k = tid - n * 384u;
        float v = qkv_w[k * 1152u + n];
        if (n < 384u) v *= 0.17677669529663687f;
        w1t[tid] = (bf16)v;
    } else if (tid < 589824u) {                // w2t[n][k] = proj_w[k][n]
        unsigned i = tid - 442368u;
        unsigned n = i / 384u, k = i - n * 384u;
        w2t[i] = (bf16)proj_w[k * 384u + n];
    } else if (tid < 638976u) {                // BT[h][b][a]
        unsigned i = tid - 589824u;
        unsigned h = i >> 12, r = i & 4095u, b = r >> 6, a = r & 63u;
        float v;
        if (b >= 49u) v = -1e9f;
        else if (a >= 49u) v = 0.0f;
        else {
            int ia = (int)(a / 7u), ja = (int)(a - 7u * (a / 7u));
            int ib = (int)(b / 7u), jb = (int)(b - 7u * (b / 7u));
            int ridx = 84 + 13 * (ia - ib) + (ja - jb);
            v = rpt[ridx * 12 + (int)h];
        }
        BT[i] = v;
    }
}

// ---------------------------------------------------------------------------
// k0x: X f32 -> bf16, 38,535,168 elems; grid 18816*256 threads * 8 elems.
// ---------------------------------------------------------------------------
__global__ __launch_bounds__(256) void k0x_cvt(
    const float* __restrict__ X, bf16* __restrict__ Xb)
{
    size_t base = ((size_t)blockIdx.x * 256u + threadIdx.x) * 8u;
    float4 lo = *(const float4*)(X + base);
    float4 hi = *(const float4*)(X + base + 4);
    *(bf16x8*)(Xb + base) = cvt8(lo, hi);
}

// ---------------------------------------------------------------------------
// k1: Y[100352][1152](bf16) = Xb(bf16) @ W1t^T + b.  BM=256 (4 waves),
// BN=64.  B in LDS once (48 KB, 3 blocks/CU); barrier-free K-loop; 4-slot
// A register prefetch ring (3-kt lookahead ~ 234 cyc covers L2-hit);
// setprio(1) around MFMA clusters.  grid = 392*18 = 7056, XCD-swizzled.
// ---------------------------------------------------------------------------
__global__ __launch_bounds__(256, 3) void k1_qkv_b(
    const bf16* __restrict__ X, const bf16* __restrict__ W,
    const float* __restrict__ bias, bf16* __restrict__ Y)
{
    __shared__ __align__(16) bf16 Bs[24576];   // 48 KB: B tile, then epi buf
    unsigned id = blockIdx.x;                  // 7056 = 8 xcd * 49 mi * 18 n
    unsigned xcd = id & 7u, seq = id >> 3;
    unsigned mi = seq / 18u, nb = seq - mi * 18u;
    unsigned mblk = xcd + (mi << 3);
    unsigned tid = threadIdx.x;
    unsigned lane = tid & 63u, wv = tid >> 6;
    unsigned ln = lane & 15u, lq = lane >> 4;
    unsigned m0 = mblk * 256u, n0 = nb * 64u;

    // stage B (64 rows x 384 k), coalesced global reads
    for (unsigned c = tid; c < 3072u; c += 256u) {
        unsigned row = c / 48u, kc = c - row * 48u, k = kc * 8u;
        unsigned blk = (k >> 5) * 4u + (row >> 4);
        unsigned l = (row & 15u) | ((kc & 3u) << 4);
        *(int4*)&Bs[(blk * 64u + l) * 8u] = *(const int4*)(W + (size_t)(n0 + row) * 384u + k);
    }

    f32x4 acc[4][4] = {};
    unsigned rbase = m0 + wv * 64u;
    const bf16* Ab = X + (size_t)(rbase + ln) * 384u + lq * 8u;

    // 4-slot prefetch ring (indices compile-time under full unroll)
    bf16x8 af[4][4];
#pragma unroll
    for (unsigned s = 0; s < 3; ++s)
#pragma unroll
        for (unsigned i = 0; i < 4; ++i)
            af[s][i] = *(const bf16x8*)(Ab + s * 32u + i * 6144u);

    __syncthreads();

#pragma unroll
    for (unsigned kt = 0; kt < 12; ++kt) {
        if (kt < 9u) {
#pragma unroll
            for (unsigned i = 0; i < 4; ++i)
                af[(kt + 3u) & 3u][i] =
                    *(const bf16x8*)(Ab + (kt + 3u) * 32u + i * 6144u);
        }
        bf16x8 bfr[4];
#pragma unroll
        for (unsigned j = 0; j < 4; ++j)
            bfr[j] = *(const bf16x8*)&Bs[((kt * 4u + j) * 64u + lane) * 8u];
        __builtin_amdgcn_s_setprio(1);
#pragma unroll
        for (unsigned i = 0; i < 4; ++i)
#pragma unroll
            for (unsigned j = 0; j < 4; ++j)
                acc[i][j] = MFMA16(af[kt & 3u][i], bfr[j], acc[i][j]);
        __builtin_amdgcn_s_setprio(0);
    }

    // bias (Q cols pre-scaled)
    float bv[4];
#pragma unroll
    for (unsigned j = 0; j < 4; ++j) {
        unsigned col = n0 + j * 16u + ln;
        bv[j] = bias[col];
        if (col < 384u) bv[j] *= 0.17677669529663687f;
    }

    // epilogue: transpose through LDS (reuse Bs, stride 72 to dodge banks),
    // then 8 coalesced bf16x8 stores per thread.
    __syncthreads();
#pragma unroll
    for (unsigned i = 0; i < 4; ++i)
#pragma unroll
        for (unsigned j = 0; j < 4; ++j)
#pragma unroll
            for (unsigned rg = 0; rg < 4; ++rg) {
                unsigned r = wv * 64u + i * 16u + lq * 4u + rg;
                Bs[r * 72u + j * 16u + ln] = (bf16)(acc[i][j][rg] + bv[j]);
            }
    __syncthreads();

#pragma unroll
    for (unsigned it = 0; it < 8; ++it) {
        unsigned idx = it * 256u + tid;
        unsigned row = idx >> 3, c8 = (idx & 7u) * 8u;
        *(bf16x8*)(Y + (size_t)(m0 + row) * 1152u + n0 + c8) =
            *(const bf16x8*)&Bs[row * 72u + c8];
    }
}

// ---------------------------------------------------------------------------
// k2: one wave per (window, head).  grid = (12, 2048), block = 64.
// Writes attn-out bf16 into Y's Q-slot (cols [0,384)).  (unchanged)
// ---------------------------------------------------------------------------
__global__ __launch_bounds__(64) void k2_attn(
    bf16* __restrict__ Y, const float* __restrict__ BT)
{
    __shared__ __align__(16) bf16 Pl[64 * 72];
    __shared__ __align__(16) bf16 Vt[32 * 72];
    unsigned h = blockIdx.x, bwin = blockIdx.y;
    unsigned bb = bwin >> 8, wi = bwin & 255u, wh = wi >> 4, ww = wi & 15u;
    unsigned lane = threadIdx.x, ln = lane & 15u, lq = lane >> 4;
    unsigned hw32 = h * 32u;

    auto pixrow = [&](unsigned t) -> unsigned {
        unsigned ti = t / 7u, tj = t - ti * 7u;
        unsigned gh = wh * 7u + ti + 3u; if (gh >= 112u) gh -= 112u;
        unsigned gw = ww * 7u + tj + 3u; if (gw >= 112u) gw -= 112u;
        return bb * 12544u + gh * 112u + gw;
    };

    // V -> LDS transposed
    {
        unsigned t = lane < 49u ? lane : 0u;
        const bf16* vs = Y + (size_t)pixrow(t) * 1152u + 768u + hw32;
        bf16x8 v0 = *(const bf16x8*)(vs);
        bf16x8 v1 = *(const bf16x8*)(vs + 8);
        bf16x8 v2 = *(const bf16x8*)(vs + 16);
        bf16x8 v3 = *(const bf16x8*)(vs + 24);
#pragma unroll
        for (int d = 0; d < 8; ++d) {
            Vt[(unsigned)(d     ) * 72u + lane] = v0[d];
            Vt[(unsigned)(d + 8 ) * 72u + lane] = v1[d];
            Vt[(unsigned)(d + 16) * 72u + lane] = v2[d];
            Vt[(unsigned)(d + 24) * 72u + lane] = v3[d];
        }
    }

    bf16x8 qf[4], kf[4];
#pragma unroll
    for (int i = 0; i < 4; ++i) {
        unsigned t = (unsigned)i * 16u + ln; t = t < 49u ? t : 0u;
        qf[i] = *(const bf16x8*)(Y + (size_t)pixrow(t) * 1152u + hw32 + lq * 8u);
    }
#pragma unroll
    for (int i = 0; i < 4; ++i) {
        unsigned t = (unsigned)i * 16u + ln; t = t < 49u ? t : 0u;
        kf[i] = *(const bf16x8*)(Y + (size_t)pixrow(t) * 1152u + 384u + hw32 + lq * 8u);
    }

    f32x4 s[4][4] = {};
#pragma unroll
    for (int i = 0; i < 4; ++i)
#pragma unroll
        for (int j = 0; j < 4; ++j)
            s[i][j] = MFMA16(qf[i], kf[j], s[i][j]);

    const float* bth = BT + h * 4096u;
#pragma unroll
    for (int i = 0; i < 4; ++i)
#pragma unroll
        for (int j = 0; j < 4; ++j) {
            f32x4 b = *(const f32x4*)(bth + ((unsigned)j * 16u + ln) * 64u +
                                      (unsigned)i * 16u + lq * 4u);
            s[i][j] += b;
        }

    if (wh == 15u || ww == 15u) {
        int ra[4][4], rb[4];
#pragma unroll
        for (int i = 0; i < 4; ++i)
#pragma unroll
            for (int rg = 0; rg < 4; ++rg) {
                unsigned a = (unsigned)i * 16u + lq * 4u + (unsigned)rg;
                unsigned ti = a / 7u, tj = a - ti * 7u;
                unsigned gh = wh * 7u + ti, gw = ww * 7u + tj;
                int rh = gh < 105u ? 0 : (gh < 109u ? 1 : 2);
                int rw = gw < 105u ? 0 : (gw < 109u ? 1 : 2);
                ra[i][rg] = rh * 3 + rw;
            }
#pragma unroll
        for (int j = 0; j < 4; ++j) {
            unsigned bc = (unsigned)j * 16u + ln;
            unsigned ti = bc / 7u, tj = bc - ti * 7u;
            unsigned gh = wh * 7u + ti, gw = ww * 7u + tj;
            int rh = gh < 105u ? 0 : (gh < 109u ? 1 : 2);
            int rw = gw < 105u ? 0 : (gw < 109u ? 1 : 2);
            rb[j] = rh * 3 + rw;
        }
#pragma unroll
        for (int i = 0; i < 4; ++i)
#pragma unroll
            for (int j = 0; j < 4; ++j)
#pragma unroll
                for (int rg = 0; rg < 4; ++rg)
                    if (ra[i][rg] != rb[j]) s[i][j][rg] -= 100.0f;
    }

    float rinv[4][4];
#pragma unroll
    for (int i = 0; i < 4; ++i)
#pragma unroll
        for (int rg = 0; rg < 4; ++rg) {
            float m = fmaxf(fmaxf(s[i][0][rg], s[i][1][rg]),
                            fmaxf(s[i][2][rg], s[i][3][rg]));
#pragma unroll
            for (int d = 8; d >= 1; d >>= 1) m = fmaxf(m, __shfl_xor(m, d, 64));
            float sum = 0.0f;
#pragma unroll
            for (int j = 0; j < 4; ++j) {
                float e = __expf(s[i][j][rg] - m);
                s[i][j][rg] = e;
                sum += e;
            }
#pragma unroll
            for (int d = 8; d >= 1; d >>= 1) sum += __shfl_xor(sum, d, 64);
            rinv[i][rg] = 1.0f / sum;
        }

#pragma unroll
    for (int i = 0; i < 4; ++i)
#pragma unroll
        for (int rg = 0; rg < 4; ++rg) {
            unsigned a = (unsigned)i * 16u + lq * 4u + (unsigned)rg;
#pragma unroll
            for (int j = 0; j < 4; ++j)
                Pl[a * 72u + (unsigned)j * 16u + ln] = (bf16)s[i][j][rg];
        }

    __syncthreads();

    f32x4 o[4][2] = {};
#pragma unroll
    for (int ks = 0; ks < 2; ++ks) {
        bf16x8 pf[4], vf[2];
#pragma unroll
        for (int i = 0; i < 4; ++i)
            pf[i] = *(const bf16x8*)&Pl[((unsigned)i * 16u + ln) * 72u +
                                        (unsigned)ks * 32u + lq * 8u];
#pragma unroll
        for (int c = 0; c < 2; ++c)
            vf[c] = *(const bf16x8*)&Vt[((unsigned)c * 16u + ln) * 72u +
                                        (unsigned)ks * 32u + lq * 8u];
#pragma unroll
        for (int i = 0; i < 4; ++i)
#pragma unroll
            for (int c = 0; c < 2; ++c)
                o[i][c] = MFMA16(pf[i], vf[c], o[i][c]);
    }

#pragma unroll
    for (int i = 0; i < 4; ++i)
#pragma unroll
        for (int rg = 0; rg < 4; ++rg) {
            unsigned a = (unsigned)i * 16u + lq * 4u + (unsigned)rg;
            if (a < 49u) {
                float ri = rinv[i][rg];
                size_t base = (size_t)pixrow(a) * 1152u + hw32;
                Y[base + ln]       = (bf16)(o[i][0][rg] * ri);
                Y[base + 16u + ln] = (bf16)(o[i][1][rg] * ri);
            }
        }
}

// ---------------------------------------------------------------------------
// k3: Out[100352][384](f32) = Ab(bf16, Y's Q-slot) @ W2t^T + b.
// Proven barrier-free structure (48 KB B once, (256,3)) + 3-slot A ring +
// setprio.  grid = 392*6 = 2352.
// ---------------------------------------------------------------------------
__global__ __launch_bounds__(256, 3) void k3_proj(
    const bf16* __restrict__ A, const bf16* __restrict__ W,
    const float* __restrict__ bias, float* __restrict__ Out)
{
    __shared__ __align__(16) bf16 Bs[24576];
    unsigned id = blockIdx.x;                  // 2352 = 8 xcd * 49 mi * 6 n
    unsigned xcd = id & 7u, seq = id >> 3;
    unsigned mi = seq / 6u, nb = seq - mi * 6u;
    unsigned mblk = xcd + (mi << 3);
    unsigned tid = threadIdx.x;
    unsigned lane = tid & 63u, wv = tid >> 6;
    unsigned ln = lane & 15u, lq = lane >> 4;
    unsigned m0 = mblk * 256u, n0 = nb * 64u;

    for (unsigned c = tid; c < 3072u; c += 256u) {
        unsigned row = c / 48u, kc = c - row * 48u, k = kc * 8u;
        unsigned blk = (k >> 5) * 4u + (row >> 4);
        unsigned l = (row & 15u) | ((kc & 3u) << 4);
        *(int4*)&Bs[(blk * 64u + l) * 8u] = *(const int4*)(W + (size_t)(n0 + row) * 384u + k);
    }

    f32x4 acc[4][4] = {};
    unsigned rbase = m0 + wv * 64u;
    const bf16* Ab = A + (size_t)(rbase + ln) * 1152u + lq * 8u;

    bf16x8 af[3][4];
#pragma unroll
    for (unsigned i = 0; i < 4; ++i) af[0][i] = *(const bf16x8*)(Ab + i * 18432u);
#pragma unroll
    for (unsigned i = 0; i < 4; ++i) af[1][i] = *(const bf16x8*)(Ab + 32u + i * 18432u);

    __syncthreads();

#pragma unroll
    for (unsigned kt = 0; kt < 12; ++kt) {
        if (kt < 10u) {
#pragma unroll
            for (unsigned i = 0; i < 4; ++i)
                af[(kt + 2u) % 3u][i] =
                    *(const bf16x8*)(Ab + (kt + 2u) * 32u + i * 18432u);
        }
        bf16x8 bfr[4];
#pragma unroll
        for (unsigned j = 0; j < 4; ++j)
            bfr[j] = *(const bf16x8*)&Bs[((kt * 4u + j) * 64u + lane) * 8u];
        __builtin_amdgcn_s_setprio(1);
#pragma unroll
        for (unsigned i = 0; i < 4; ++i)
#pragma unroll
            for (unsigned j = 0; j < 4; ++j)
                acc[i][j] = MFMA16(af[kt % 3u][i], bfr[j], acc[i][j]);
        __builtin_amdgcn_s_setprio(0);
    }

#pragma unroll
    for (unsigned j = 0; j < 4; ++j) {
        unsigned col = n0 + j * 16u + ln;
        float bv = bias[col];
#pragma unroll
        for (unsigned i = 0; i < 4; ++i) {
            unsigned row = rbase + i * 16u + lq * 4u;
#pragma unroll
            for (unsigned rg = 0; rg < 4; ++rg)
                Out[(size_t)(row + rg) * 384u + col] = acc[i][j][rg] + bv;
        }
    }
}

// ---------------------------------------------------------------------------
// launch
// ---------------------------------------------------------------------------
extern "C" void kernel_launch(void* const* d_in, const int* in_sizes, int n_in,
                              void* d_out, int out_size, void* d_ws, size_t ws_size,
                              hipStream_t stream) {
    const float* x      = (const float*)d_in[0];
    const float* qkv_w  = (const float*)d_in[1];
    const float* qkv_b  = (const float*)d_in[2];
    const float* proj_w = (const float*)d_in[3];
    const float* proj_b = (const float*)d_in[4];
    const float* rpt    = (const float*)d_in[5];
    (void)in_sizes; (void)n_in; (void)out_size; (void)ws_size;

    char* ws = (char*)d_ws;
    bf16*  Y   = (bf16*)(ws);                       // 231,211,008 B
    bf16*  w1t = (bf16*)(ws + 231211008u);          //     884,736 B
    bf16*  w2t = (bf16*)(ws + 232095744u);          //     294,912 B
    float* BT  = (float*)(ws + 232390656u);         //     196,608 B
    bf16*  Xb  = (bf16*)(ws + 232587264u);          //  77,070,336 B
    float* out = (float*)d_out;

    k0_prep<<<2496, 256, 0, stream>>>(qkv_w, proj_w, rpt, w1t, w2t, BT);
    k0x_cvt<<<18816, 256, 0, stream>>>(x, Xb);
    k1_qkv_b<<<7056, 256, 0, stream>>>(Xb, w1t, qkv_b, Y);
    k2_attn<<<dim3(12, 2048), 64, 0, stream>>>(Y, BT);
    k3_proj<<<2352, 256, 0, stream>>>(Y, w2t, proj_b, out);
}